// Round 2
// baseline (207.040 us; speedup 1.0000x reference)
//
#include <hip/hip_runtime.h>

// N0=N1=100000, K=16, D_MODEL=64, D_ATTN=32, H=4, dh_attn=8, dh_val=16
// KVh row (104 halfs = 208B): [0:32) K f16 | [32:96) V f16 | [96:104) coords0 as f32x4
// Q  = feats1 @ Wq + bq -> f32 [n1][32]   (MFMA f16)
// attn: logit = q.K0[idx] + rel.(q@Wk3) ; softmax ; out = sum_j a_j V0[idx_j] + rbar@Wv3
// r6: all cross-lane exchange via DPP row_ror (VALU) + per-point LDS parity scratch.
//     DS ops/wave ~13 (was ~103 ds_bpermute). coords0 embedded in KV row: 1 float4
//     gather instead of 3 divergent scalar loads.

using half8   = __attribute__((ext_vector_type(8))) _Float16;
using floatx4 = __attribute__((ext_vector_type(4))) float;

template<int CTRL>
__device__ __forceinline__ float dppAdd(float x) {
    int y = __builtin_amdgcn_update_dpp(0, __float_as_int(x), CTRL, 0xF, 0xF, true);
    return x + __int_as_float(y);
}
// sum of all 16 lanes within each 16-lane row, result in every lane
__device__ __forceinline__ float rowSum16(float x) {
    x = dppAdd<0x121>(x);   // row_ror:1
    x = dppAdd<0x122>(x);   // row_ror:2
    x = dppAdd<0x124>(x);   // row_ror:4
    x = dppAdd<0x128>(x);   // row_ror:8
    return x;
}

// ---------------------------------------------------------------------------
// Fused projection kernel. Blocks [0,nb0): KV tiles of feats0 (+coords0 tail).
// Blocks [nb0,nb0+nb1): Q tiles.
// ---------------------------------------------------------------------------
__global__ __launch_bounds__(256, 4) void proj_fused(
    const float* __restrict__ coords0,
    const float* __restrict__ feats0, const float* __restrict__ feats1,
    const float* __restrict__ Wq, const float* __restrict__ bq,
    const float* __restrict__ Wk, const float* __restrict__ bk,
    const float* __restrict__ Wv, const float* __restrict__ bv,
    _Float16* __restrict__ KVh, float* __restrict__ Qf,
    int n0, int n1, int nb0)
{
    __shared__ __align__(16) _Float16 sFrag[6144];
    __shared__ __align__(16) _Float16 sOut[6656];   // 64 rows x 104 halfs

    const int tid  = threadIdx.x;
    const int wave = tid >> 6;
    const int lane = tid & 63;
    const int l15  = lane & 15;
    const int quad = lane >> 4;

    if ((int)blockIdx.x < nb0) {
        const int rowBase = blockIdx.x * 64;
        for (int e = tid; e < 6144; e += 256) {
            int j = e & 7, ln = (e >> 3) & 63, h = (e >> 9) & 1, t = e >> 10;
            int k = h * 32 + ((ln >> 4) * 8) + j;
            int n = t * 16 + (ln & 15);
            float v = (n < 32) ? Wk[k * 32 + n] : Wv[k * 64 + (n - 32)];
            sFrag[e] = (_Float16)v;
        }
        __syncthreads();

        const int m0   = rowBase + wave * 16;
        const int row  = m0 + l15;
        const int rowc = (row < n0) ? row : (n0 - 1);
        const floatx4* X4 = (const floatx4*)(feats0 + (size_t)rowc * 64);
        floatx4 f0 = X4[quad * 2 + 0], f1 = X4[quad * 2 + 1];
        floatx4 f2 = X4[quad * 2 + 8], f3 = X4[quad * 2 + 9];
        half8 a0, a1;
        a0[0]=(_Float16)f0.x; a0[1]=(_Float16)f0.y; a0[2]=(_Float16)f0.z; a0[3]=(_Float16)f0.w;
        a0[4]=(_Float16)f1.x; a0[5]=(_Float16)f1.y; a0[6]=(_Float16)f1.z; a0[7]=(_Float16)f1.w;
        a1[0]=(_Float16)f2.x; a1[1]=(_Float16)f2.y; a1[2]=(_Float16)f2.z; a1[3]=(_Float16)f2.w;
        a1[4]=(_Float16)f3.x; a1[5]=(_Float16)f3.y; a1[6]=(_Float16)f3.z; a1[7]=(_Float16)f3.w;

        const half8* bf = (const half8*)sFrag;
        floatx4 acc[6];
        #pragma unroll
        for (int t = 0; t < 6; t++) {
            int n = t * 16 + l15;
            float bb = (n < 32) ? bk[n] : bv[n - 32];
            acc[t] = (floatx4){bb, bb, bb, bb};
        }
        #pragma unroll
        for (int t = 0; t < 6; t++) {
            acc[t] = __builtin_amdgcn_mfma_f32_16x16x32_f16(a0, bf[(t*2+0)*64 + lane], acc[t], 0,0,0);
            acc[t] = __builtin_amdgcn_mfma_f32_16x16x32_f16(a1, bf[(t*2+1)*64 + lane], acc[t], 0,0,0);
        }

        #pragma unroll
        for (int t = 0; t < 6; t++)
            #pragma unroll
            for (int r = 0; r < 4; r++)
                sOut[(wave * 16 + quad * 4 + r) * 104 + t * 16 + l15] = (_Float16)acc[t][r];

        // stage coords0 into the row tail as f32 (halfs 96..103 = 16B)
        for (int r2 = tid; r2 < 64; r2 += 256) {
            int rr = rowBase + r2;
            int rc = (rr < n0) ? rr : (n0 - 1);
            float* cw = (float*)(sOut + r2 * 104 + 96);
            cw[0] = coords0[(size_t)rc * 3 + 0];
            cw[1] = coords0[(size_t)rc * 3 + 1];
            cw[2] = coords0[(size_t)rc * 3 + 2];
            cw[3] = 0.f;
        }
        __syncthreads();

        const half8* so8 = (const half8*)sOut;
        half8* dst = (half8*)(KVh + (size_t)rowBase * 104);
        for (int c = tid; c < 832; c += 256) {     // 64 rows x 13 chunks
            int r = c / 13;
            if (rowBase + r < n0) dst[c] = so8[c];
        }
    } else {
        const int rowBase = ((int)blockIdx.x - nb0) * 64;
        for (int e = tid; e < 2048; e += 256) {
            int j = e & 7, ln = (e >> 3) & 63, h = (e >> 9) & 1, t = e >> 10;
            int k = h * 32 + ((ln >> 4) * 8) + j;
            int n = t * 16 + (ln & 15);
            sFrag[e] = (_Float16)Wq[k * 32 + n];
        }
        __syncthreads();

        const int m0   = rowBase + wave * 16;
        const int row  = m0 + l15;
        const int rowc = (row < n1) ? row : (n1 - 1);
        const floatx4* X4 = (const floatx4*)(feats1 + (size_t)rowc * 64);
        floatx4 f0 = X4[quad * 2 + 0], f1 = X4[quad * 2 + 1];
        floatx4 f2 = X4[quad * 2 + 8], f3 = X4[quad * 2 + 9];
        half8 a0, a1;
        a0[0]=(_Float16)f0.x; a0[1]=(_Float16)f0.y; a0[2]=(_Float16)f0.z; a0[3]=(_Float16)f0.w;
        a0[4]=(_Float16)f1.x; a0[5]=(_Float16)f1.y; a0[6]=(_Float16)f1.z; a0[7]=(_Float16)f1.w;
        a1[0]=(_Float16)f2.x; a1[1]=(_Float16)f2.y; a1[2]=(_Float16)f2.z; a1[3]=(_Float16)f2.w;
        a1[4]=(_Float16)f3.x; a1[5]=(_Float16)f3.y; a1[6]=(_Float16)f3.z; a1[7]=(_Float16)f3.w;

        const half8* bf = (const half8*)sFrag;
        floatx4 acc[2];
        #pragma unroll
        for (int t = 0; t < 2; t++) {
            float bb = bq[t * 16 + l15];
            acc[t] = (floatx4){bb, bb, bb, bb};
        }
        #pragma unroll
        for (int t = 0; t < 2; t++) {
            acc[t] = __builtin_amdgcn_mfma_f32_16x16x32_f16(a0, bf[(t*2+0)*64 + lane], acc[t], 0,0,0);
            acc[t] = __builtin_amdgcn_mfma_f32_16x16x32_f16(a1, bf[(t*2+1)*64 + lane], acc[t], 0,0,0);
        }
        #pragma unroll
        for (int t = 0; t < 2; t++)
            #pragma unroll
            for (int r = 0; r < 4; r++) {
                int ro = m0 + quad * 4 + r;
                if (ro < n1) Qf[(size_t)ro * 32 + t * 16 + l15] = acc[t][r];
            }
    }
}

// ---------------------------------------------------------------------------
// Attention, wave-synchronous. 16 lanes/point, 4 points/wave, 16 points/block.
// Cross-lane: DPP row_ror reductions (VALU) + per-point LDS parity scratch.
// ---------------------------------------------------------------------------
__global__ __launch_bounds__(256, 4) void attn_kernel(
    const float* __restrict__ coords1,
    const int*   __restrict__ knn,
    const float* __restrict__ Qf, const _Float16* __restrict__ KVh,
    const float* __restrict__ Wk, const float* __restrict__ Wv,
    float* __restrict__ out, float* __restrict__ outIdx, int n1)
{
    __shared__ __align__(16) float sQ[16][36];
    __shared__ float sWk3[3][32];
    __shared__ float sWv3[3][64];
    __shared__ __align__(16) float sT[16][12];    // tt[c][h2] at [p][c*4+h2]
    __shared__ __align__(16) int   sIdx[16][16];  // parity layout [p][(j&1)*8 + (j>>1)]
    __shared__ __align__(16) float sA[16][68];    // [p][h*16 + parity*8 + slot] (+4 pad)

    const int tid = threadIdx.x;
    for (int e = tid; e < 288; e += 256) {
        if (e < 96) ((float*)sWk3)[e] = Wk[2048 + e];
        else        ((float*)sWv3)[e - 96] = Wv[4096 + (e - 96)];
    }
    if (tid < 128) {                      // stage Q rows for the block's 16 points
        int pt = tid >> 3, c4 = tid & 7;
        int r = blockIdx.x * 16 + pt;
        if (r >= n1) r = n1 - 1;
        ((floatx4*)&sQ[pt][0])[c4] = ((const floatx4*)Qf)[(size_t)r * 8 + c4];
    }
    __syncthreads();   // the only block barrier

    const int p = tid >> 4;          // point in block (0..15); 16-lane DPP row
    const int j = tid & 15;          // lane within point = neighbor id
    const int n = blockIdx.x * 16 + p;
    const bool valid = (n < n1);
    const int nc = valid ? n : (n1 - 1);

    const int idx = knn[nc * 16 + j];                       // own neighbor index

    // K row (64B) + coords (16B) from the same KV row
    const half8* kr = (const half8*)(KVh + (size_t)idx * 104);
    half8 k8_0 = kr[0], k8_1 = kr[1], k8_2 = kr[2], k8_3 = kr[3];
    floatx4 cg = *(const floatx4*)(KVh + (size_t)idx * 104 + 96);

    const float r0 = cg[0] - coords1[nc * 3 + 0];
    const float r1 = cg[1] - coords1[nc * 3 + 1];
    const float r2 = cg[2] - coords1[nc * 3 + 2];

    const int g    = j & 7;          // dim group for phase 2: dims [8g, 8g+8)
    const int hf   = j >> 3;         // parity of neighbors this lane accumulates
    const int h    = g >> 1;         // head owning dims [8g, 8g+8)
    const int slot = ((j & 1) << 3) + (j >> 1);   // parity-major slot

    sIdx[p][slot] = idx;

    // tt[c][h2] = q_h2 . Wk3[c, h2*8:+8]  (12 lanes compute, LDS broadcast)
    if (j < 12) {
        int c = j >> 2, h2 = j & 3;
        float t = 0.f;
        #pragma unroll
        for (int i = 0; i < 8; i++)
            t = fmaf(sWk3[c][h2 * 8 + i], sQ[p][h2 * 8 + i], t);
        sT[p][j] = t;
    }

    // V gather addresses from parity scratch (same wave: in-order LDS)
    const int4* si4 = (const int4*)&sIdx[p][hf * 8];
    int4 viA = si4[0], viB = si4[1];
    int vIdx[8] = {viA.x, viA.y, viA.z, viA.w, viB.x, viB.y, viB.z, viB.w};
    half8 v8[8];
    #pragma unroll
    for (int s = 0; s < 8; s++)
        v8[s] = *(const half8*)(KVh + (size_t)vIdx[s] * 104 + 32 + g * 8);

    const floatx4* t4 = (const floatx4*)&sT[p][0];
    floatx4 tc0 = t4[0], tc1 = t4[1], tc2 = t4[2];   // tt[c][0..3]

    // ---- logits + softmax (DPP row sums) ----
    const float scale = 0.35355339059327373f;  // 1/sqrt(8)
    float a_h[4];
    {
        half8 k8[4] = {k8_0, k8_1, k8_2, k8_3};
        #pragma unroll
        for (int h2 = 0; h2 < 4; h2++) {
            floatx4 q0 = ((const floatx4*)&sQ[p][0])[h2 * 2 + 0];
            floatx4 q1 = ((const floatx4*)&sQ[p][0])[h2 * 2 + 1];
            float acc = r0 * tc0[h2] + r1 * tc1[h2] + r2 * tc2[h2];
            acc = fmaf(q0[0], (float)k8[h2][0], acc);
            acc = fmaf(q0[1], (float)k8[h2][1], acc);
            acc = fmaf(q0[2], (float)k8[h2][2], acc);
            acc = fmaf(q0[3], (float)k8[h2][3], acc);
            acc = fmaf(q1[0], (float)k8[h2][4], acc);
            acc = fmaf(q1[1], (float)k8[h2][5], acc);
            acc = fmaf(q1[2], (float)k8[h2][6], acc);
            acc = fmaf(q1[3], (float)k8[h2][7], acc);
            float e = __expf(acc * scale);      // |logit*scale| small: no max-sub
            float ssum = rowSum16(e);
            a_h[h2] = e * __builtin_amdgcn_rcpf(ssum);
        }
    }

    // attn weights to parity scratch
    sA[p][0 * 16 + slot] = a_h[0];
    sA[p][1 * 16 + slot] = a_h[1];
    sA[p][2 * 16 + slot] = a_h[2];
    sA[p][3 * 16 + slot] = a_h[3];

    if (valid) outIdx[n * 16 + j] = (float)idx;

    // rbar[c] per head via DPP full-row sums (no LDS, no regs held across loop)
    float rbs0, rbs1, rbs2;
    {
        float s00 = rowSum16(a_h[0] * r0), s01 = rowSum16(a_h[1] * r0);
        float s02 = rowSum16(a_h[2] * r0), s03 = rowSum16(a_h[3] * r0);
        rbs0 = (h == 0) ? s00 : (h == 1) ? s01 : (h == 2) ? s02 : s03;
        float s10 = rowSum16(a_h[0] * r1), s11 = rowSum16(a_h[1] * r1);
        float s12 = rowSum16(a_h[2] * r1), s13 = rowSum16(a_h[3] * r1);
        rbs1 = (h == 0) ? s10 : (h == 1) ? s11 : (h == 2) ? s12 : s13;
        float s20 = rowSum16(a_h[0] * r2), s21 = rowSum16(a_h[1] * r2);
        float s22 = rowSum16(a_h[2] * r2), s23 = rowSum16(a_h[3] * r2);
        rbs2 = (h == 0) ? s20 : (h == 1) ? s21 : (h == 2) ? s22 : s23;
    }

    // own head's weights for parity hf, contiguous over s
    const floatx4* a4 = (const floatx4*)&sA[p][h * 16 + hf * 8];
    floatx4 aw0 = a4[0], aw1 = a4[1];
    float av[8] = {aw0[0], aw0[1], aw0[2], aw0[3], aw1[0], aw1[1], aw1[2], aw1[3]};

    // ---- phase 2: weighted V sum ----
    float acc8[8] = {0,0,0,0,0,0,0,0};
    #pragma unroll
    for (int s = 0; s < 8; s++)
        #pragma unroll
        for (int i = 0; i < 8; i++)
            acc8[i] = fmaf(av[s], (float)v8[s][i], acc8[i]);

    #pragma unroll
    for (int i = 0; i < 8; i++) acc8[i] = dppAdd<0x128>(acc8[i]);  // + other parity

    #pragma unroll
    for (int i = 0; i < 8; i++)
        acc8[i] += rbs0 * sWv3[0][8 * g + i] + rbs1 * sWv3[1][8 * g + i] + rbs2 * sWv3[2][8 * g + i];

    if (valid) {
        floatx4 st = { acc8[hf * 4 + 0], acc8[hf * 4 + 1], acc8[hf * 4 + 2], acc8[hf * 4 + 3] };
        ((floatx4*)out)[(size_t)n * 16 + g * 2 + hf] = st;
    }
}

// ---------------------------------------------------------------------------
extern "C" void kernel_launch(void* const* d_in, const int* in_sizes, int n_in,
                              void* d_out, int out_size, void* d_ws, size_t ws_size,
                              hipStream_t stream) {
    const float* coords0 = (const float*)d_in[0];
    const float* coords1 = (const float*)d_in[1];
    const float* feats0  = (const float*)d_in[2];
    const float* feats1  = (const float*)d_in[3];
    const int*   knn     = (const int*)d_in[4];
    const float* Wq      = (const float*)d_in[5];
    const float* bq      = (const float*)d_in[6];
    const float* Wk      = (const float*)d_in[7];
    const float* bk      = (const float*)d_in[8];
    const float* Wv      = (const float*)d_in[9];
    const float* bv      = (const float*)d_in[10];

    const int n0 = in_sizes[0] / 3;
    const int n1 = in_sizes[1] / 3;

    char* ws = (char*)d_ws;
    _Float16* KVh = (_Float16*)ws;                          // [n0][104] f16 (+coords tail)
    float*    Qf  = (float*)(ws + (size_t)n0 * 104 * 2);    // [n1][32] f32

    float* out    = (float*)d_out;                          // [n1,64]
    float* outIdx = out + (size_t)n1 * 64;                  // [1,n1,16] as float

    const int nb0 = (n0 + 63) / 64;
    const int nb1 = (n1 + 63) / 64;

    proj_fused<<<nb0 + nb1, 256, 0, stream>>>(coords0, feats0, feats1,
                                              Wq, bq, Wk, bk, Wv, bv,
                                              KVh, Qf, n0, n1, nb0);
    attn_kernel<<<(n1 + 15) / 16, 256, 0, stream>>>(coords1, knn,
                                                    Qf, KVh, Wk, Wv, out, outIdx, n1);
}

// Round 4
// 188.501 us; speedup vs baseline: 1.0983x; 1.0983x over previous
//
#include <hip/hip_runtime.h>

// N0=N1=100000, K=16, D_MODEL=64, D_ATTN=32, H=4, dh_attn=8, dh_val=16
// KVh row (96 halfs = 192B): [0:32) K f16 | [32:96) V f16.  coords0 read directly
// (1.2MB, L2-resident).  Q = feats1 @ Wq + bq -> f32 [n1][32].
// r7: revert r6's coords-embedding (it inflated gather fetch 256->336B/row).
//     Keep DPP row-sums + LDS parity scratch. Weight MFMA fragments are
//     precomputed once by prep_weights; proj stages them as half8 vector copies.

using half8   = __attribute__((ext_vector_type(8))) _Float16;
using floatx4 = __attribute__((ext_vector_type(4))) float;

template<int CTRL>
__device__ __forceinline__ float dppAdd(float x) {
    int y = __builtin_amdgcn_update_dpp(0, __float_as_int(x), CTRL, 0xF, 0xF, true);
    return x + __int_as_float(y);
}
// sum of all 16 lanes within each 16-lane row, result in every lane
__device__ __forceinline__ float rowSum16(float x) {
    x = dppAdd<0x121>(x);   // row_ror:1
    x = dppAdd<0x122>(x);   // row_ror:2
    x = dppAdd<0x124>(x);   // row_ror:4
    x = dppAdd<0x128>(x);   // row_ror:8
    return x;
}

// ---------------------------------------------------------------------------
// One-shot: build the MFMA B-fragment layouts for [Wk|Wv] (6144 halfs) and
// Wq (2048 halfs). Runs once; proj blocks then vector-copy these into LDS.
// ---------------------------------------------------------------------------
__global__ __launch_bounds__(256) void prep_weights(
    const float* __restrict__ Wq, const float* __restrict__ Wk,
    const float* __restrict__ Wv,
    _Float16* __restrict__ fragKV, _Float16* __restrict__ fragQ)
{
    const int base = blockIdx.x * 256 + threadIdx.x;
    for (int e = base; e < 6144; e += 2048) {
        int j = e & 7, ln = (e >> 3) & 63, h = (e >> 9) & 1, t = e >> 10;
        int k = h * 32 + ((ln >> 4) * 8) + j;
        int n = t * 16 + (ln & 15);
        float v = (n < 32) ? Wk[k * 32 + n] : Wv[k * 64 + (n - 32)];
        fragKV[e] = (_Float16)v;
    }
    for (int e = base; e < 2048; e += 2048) {
        int j = e & 7, ln = (e >> 3) & 63, h = (e >> 9) & 1, t = e >> 10;
        int k = h * 32 + ((ln >> 4) * 8) + j;
        int n = t * 16 + (ln & 15);
        fragQ[e] = (_Float16)Wq[k * 32 + n];
    }
}

// ---------------------------------------------------------------------------
// Fused projection kernel. Blocks [0,nb0): KV tiles of feats0.
// Blocks [nb0,nb0+nb1): Q tiles.
// ---------------------------------------------------------------------------
__global__ __launch_bounds__(256, 4) void proj_fused(
    const float* __restrict__ feats0, const float* __restrict__ feats1,
    const _Float16* __restrict__ fragKV, const _Float16* __restrict__ fragQ,
    const float* __restrict__ bq, const float* __restrict__ bk,
    const float* __restrict__ bv,
    _Float16* __restrict__ KVh, float* __restrict__ Qf,
    int n0, int n1, int nb0)
{
    __shared__ __align__(16) _Float16 sFrag[6144];
    __shared__ __align__(16) _Float16 sOut[6144];

    const int tid  = threadIdx.x;
    const int wave = tid >> 6;
    const int lane = tid & 63;
    const int l15  = lane & 15;
    const int quad = lane >> 4;

    if ((int)blockIdx.x < nb0) {
        const int rowBase = blockIdx.x * 64;
        half8* sF8 = (half8*)sFrag;
        const half8* fk8 = (const half8*)fragKV;
        for (int c = tid; c < 768; c += 256) sF8[c] = fk8[c];
        __syncthreads();

        const int m0   = rowBase + wave * 16;
        const int row  = m0 + l15;
        const int rowc = (row < n0) ? row : (n0 - 1);
        const floatx4* X4 = (const floatx4*)(feats0 + (size_t)rowc * 64);
        floatx4 f0 = X4[quad * 2 + 0], f1 = X4[quad * 2 + 1];
        floatx4 f2 = X4[quad * 2 + 8], f3 = X4[quad * 2 + 9];
        half8 a0, a1;
        a0[0]=(_Float16)f0.x; a0[1]=(_Float16)f0.y; a0[2]=(_Float16)f0.z; a0[3]=(_Float16)f0.w;
        a0[4]=(_Float16)f1.x; a0[5]=(_Float16)f1.y; a0[6]=(_Float16)f1.z; a0[7]=(_Float16)f1.w;
        a1[0]=(_Float16)f2.x; a1[1]=(_Float16)f2.y; a1[2]=(_Float16)f2.z; a1[3]=(_Float16)f2.w;
        a1[4]=(_Float16)f3.x; a1[5]=(_Float16)f3.y; a1[6]=(_Float16)f3.z; a1[7]=(_Float16)f3.w;

        const half8* bf = (const half8*)sFrag;
        floatx4 acc[6];
        #pragma unroll
        for (int t = 0; t < 6; t++) {
            int n = t * 16 + l15;
            float bb = (n < 32) ? bk[n] : bv[n - 32];
            acc[t] = (floatx4){bb, bb, bb, bb};
        }
        #pragma unroll
        for (int t = 0; t < 6; t++) {
            acc[t] = __builtin_amdgcn_mfma_f32_16x16x32_f16(a0, bf[(t*2+0)*64 + lane], acc[t], 0,0,0);
            acc[t] = __builtin_amdgcn_mfma_f32_16x16x32_f16(a1, bf[(t*2+1)*64 + lane], acc[t], 0,0,0);
        }

        #pragma unroll
        for (int t = 0; t < 6; t++)
            #pragma unroll
            for (int r = 0; r < 4; r++)
                sOut[(wave * 16 + quad * 4 + r) * 96 + t * 16 + l15] = (_Float16)acc[t][r];
        __syncthreads();

        const half8* so8 = (const half8*)sOut;
        half8* dst = (half8*)(KVh + (size_t)rowBase * 96);
        for (int c = tid; c < 768; c += 256) {
            int r = c / 12;
            if (rowBase + r < n0) dst[c] = so8[c];
        }
    } else {
        const int rowBase = ((int)blockIdx.x - nb0) * 64;
        half8* sF8 = (half8*)sFrag;
        const half8* fq8 = (const half8*)fragQ;
        for (int c = tid; c < 256; c += 256) sF8[c] = fq8[c];
        __syncthreads();

        const int m0   = rowBase + wave * 16;
        const int row  = m0 + l15;
        const int rowc = (row < n1) ? row : (n1 - 1);
        const floatx4* X4 = (const floatx4*)(feats1 + (size_t)rowc * 64);
        floatx4 f0 = X4[quad * 2 + 0], f1 = X4[quad * 2 + 1];
        floatx4 f2 = X4[quad * 2 + 8], f3 = X4[quad * 2 + 9];
        half8 a0, a1;
        a0[0]=(_Float16)f0.x; a0[1]=(_Float16)f0.y; a0[2]=(_Float16)f0.z; a0[3]=(_Float16)f0.w;
        a0[4]=(_Float16)f1.x; a0[5]=(_Float16)f1.y; a0[6]=(_Float16)f1.z; a0[7]=(_Float16)f1.w;
        a1[0]=(_Float16)f2.x; a1[1]=(_Float16)f2.y; a1[2]=(_Float16)f2.z; a1[3]=(_Float16)f2.w;
        a1[4]=(_Float16)f3.x; a1[5]=(_Float16)f3.y; a1[6]=(_Float16)f3.z; a1[7]=(_Float16)f3.w;

        const half8* bf = (const half8*)sFrag;
        floatx4 acc[2];
        #pragma unroll
        for (int t = 0; t < 2; t++) {
            float bb = bq[t * 16 + l15];
            acc[t] = (floatx4){bb, bb, bb, bb};
        }
        #pragma unroll
        for (int t = 0; t < 2; t++) {
            acc[t] = __builtin_amdgcn_mfma_f32_16x16x32_f16(a0, bf[(t*2+0)*64 + lane], acc[t], 0,0,0);
            acc[t] = __builtin_amdgcn_mfma_f32_16x16x32_f16(a1, bf[(t*2+1)*64 + lane], acc[t], 0,0,0);
        }
        #pragma unroll
        for (int t = 0; t < 2; t++)
            #pragma unroll
            for (int r = 0; r < 4; r++) {
                int ro = m0 + quad * 4 + r;
                if (ro < n1) Qf[(size_t)ro * 32 + t * 16 + l15] = acc[t][r];
            }
    }
}

// ---------------------------------------------------------------------------
// Attention, wave-synchronous. 16 lanes/point, 4 points/wave, 16 points/block.
// Cross-lane: DPP row_ror reductions (VALU) + per-point LDS parity scratch.
// ---------------------------------------------------------------------------
__global__ __launch_bounds__(256, 4) void attn_kernel(
    const float* __restrict__ coords0, const float* __restrict__ coords1,
    const int*   __restrict__ knn,
    const float* __restrict__ Qf, const _Float16* __restrict__ KVh,
    const float* __restrict__ Wk, const float* __restrict__ Wv,
    float* __restrict__ out, float* __restrict__ outIdx, int n1)
{
    __shared__ __align__(16) float sQ[16][36];
    __shared__ float sWk3[3][32];
    __shared__ float sWv3[3][64];
    __shared__ __align__(16) float sT[16][12];    // tt[c][h2] at [p][c*4+h2]
    __shared__ __align__(16) int   sIdx[16][16];  // parity layout [p][(j&1)*8 + (j>>1)]
    __shared__ __align__(16) float sA[16][68];    // [p][h*16 + parity*8 + slot] (+4 pad)

    const int tid = threadIdx.x;
    for (int e = tid; e < 288; e += 256) {
        if (e < 96) ((float*)sWk3)[e] = Wk[2048 + e];
        else        ((float*)sWv3)[e - 96] = Wv[4096 + (e - 96)];
    }
    if (tid < 128) {                      // stage Q rows for the block's 16 points
        int pt = tid >> 3, c4 = tid & 7;
        int r = blockIdx.x * 16 + pt;
        if (r >= n1) r = n1 - 1;
        ((floatx4*)&sQ[pt][0])[c4] = ((const floatx4*)Qf)[(size_t)r * 8 + c4];
    }
    __syncthreads();   // the only block barrier

    const int p = tid >> 4;          // point in block (0..15); 16-lane DPP row
    const int j = tid & 15;          // lane within point = neighbor id
    const int n = blockIdx.x * 16 + p;
    const bool valid = (n < n1);
    const int nc = valid ? n : (n1 - 1);

    const int idx = knn[nc * 16 + j];                       // own neighbor index

    // K row (64B); coords0 separately (1.2MB, L2-resident)
    const half8* kr = (const half8*)(KVh + (size_t)idx * 96);
    half8 k8_0 = kr[0], k8_1 = kr[1], k8_2 = kr[2], k8_3 = kr[3];

    const float r0 = coords0[idx * 3 + 0] - coords1[nc * 3 + 0];
    const float r1 = coords0[idx * 3 + 1] - coords1[nc * 3 + 1];
    const float r2 = coords0[idx * 3 + 2] - coords1[nc * 3 + 2];

    const int g    = j & 7;          // dim group for phase 2: dims [8g, 8g+8)
    const int hf   = j >> 3;         // parity of neighbors this lane accumulates
    const int h    = g >> 1;         // head owning dims [8g, 8g+8)
    const int slot = ((j & 1) << 3) + (j >> 1);   // parity-major slot

    sIdx[p][slot] = idx;

    // tt[c][h2] = q_h2 . Wk3[c, h2*8:+8]  (12 lanes compute, LDS broadcast)
    if (j < 12) {
        int c = j >> 2, h2 = j & 3;
        float t = 0.f;
        #pragma unroll
        for (int i = 0; i < 8; i++)
            t = fmaf(sWk3[c][h2 * 8 + i], sQ[p][h2 * 8 + i], t);
        sT[p][j] = t;
    }

    // V gather addresses from parity scratch (same wave: in-order LDS)
    const int4* si4 = (const int4*)&sIdx[p][hf * 8];
    int4 viA = si4[0], viB = si4[1];
    int vIdx[8] = {viA.x, viA.y, viA.z, viA.w, viB.x, viB.y, viB.z, viB.w};
    half8 v8[8];
    #pragma unroll
    for (int s = 0; s < 8; s++)
        v8[s] = *(const half8*)(KVh + (size_t)vIdx[s] * 96 + 32 + g * 8);

    const floatx4* t4 = (const floatx4*)&sT[p][0];
    floatx4 tc0 = t4[0], tc1 = t4[1], tc2 = t4[2];   // tt[c][0..3]

    // ---- logits + softmax (DPP row sums) ----
    const float scale = 0.35355339059327373f;  // 1/sqrt(8)
    float a_h[4];
    {
        half8 k8[4] = {k8_0, k8_1, k8_2, k8_3};
        #pragma unroll
        for (int h2 = 0; h2 < 4; h2++) {
            floatx4 q0 = ((const floatx4*)&sQ[p][0])[h2 * 2 + 0];
            floatx4 q1 = ((const floatx4*)&sQ[p][0])[h2 * 2 + 1];
            float acc = r0 * tc0[h2] + r1 * tc1[h2] + r2 * tc2[h2];
            acc = fmaf(q0[0], (float)k8[h2][0], acc);
            acc = fmaf(q0[1], (float)k8[h2][1], acc);
            acc = fmaf(q0[2], (float)k8[h2][2], acc);
            acc = fmaf(q0[3], (float)k8[h2][3], acc);
            acc = fmaf(q1[0], (float)k8[h2][4], acc);
            acc = fmaf(q1[1], (float)k8[h2][5], acc);
            acc = fmaf(q1[2], (float)k8[h2][6], acc);
            acc = fmaf(q1[3], (float)k8[h2][7], acc);
            float e = __expf(acc * scale);      // |logit*scale| small: no max-sub
            float ssum = rowSum16(e);
            a_h[h2] = e * __builtin_amdgcn_rcpf(ssum);
        }
    }

    // attn weights to parity scratch
    sA[p][0 * 16 + slot] = a_h[0];
    sA[p][1 * 16 + slot] = a_h[1];
    sA[p][2 * 16 + slot] = a_h[2];
    sA[p][3 * 16 + slot] = a_h[3];

    if (valid) outIdx[n * 16 + j] = (float)idx;

    // rbar[c] per head via DPP full-row sums
    float rbs0, rbs1, rbs2;
    {
        float s00 = rowSum16(a_h[0] * r0), s01 = rowSum16(a_h[1] * r0);
        float s02 = rowSum16(a_h[2] * r0), s03 = rowSum16(a_h[3] * r0);
        rbs0 = (h == 0) ? s00 : (h == 1) ? s01 : (h == 2) ? s02 : s03;
        float s10 = rowSum16(a_h[0] * r1), s11 = rowSum16(a_h[1] * r1);
        float s12 = rowSum16(a_h[2] * r1), s13 = rowSum16(a_h[3] * r1);
        rbs1 = (h == 0) ? s10 : (h == 1) ? s11 : (h == 2) ? s12 : s13;
        float s20 = rowSum16(a_h[0] * r2), s21 = rowSum16(a_h[1] * r2);
        float s22 = rowSum16(a_h[2] * r2), s23 = rowSum16(a_h[3] * r2);
        rbs2 = (h == 0) ? s20 : (h == 1) ? s21 : (h == 2) ? s22 : s23;
    }

    // own head's weights for parity hf, contiguous over s
    const floatx4* a4 = (const floatx4*)&sA[p][h * 16 + hf * 8];
    floatx4 aw0 = a4[0], aw1 = a4[1];
    float av[8] = {aw0[0], aw0[1], aw0[2], aw0[3], aw1[0], aw1[1], aw1[2], aw1[3]};

    // ---- phase 2: weighted V sum ----
    float acc8[8] = {0,0,0,0,0,0,0,0};
    #pragma unroll
    for (int s = 0; s < 8; s++)
        #pragma unroll
        for (int i = 0; i < 8; i++)
            acc8[i] = fmaf(av[s], (float)v8[s][i], acc8[i]);

    #pragma unroll
    for (int i = 0; i < 8; i++) acc8[i] = dppAdd<0x128>(acc8[i]);  // + other parity

    #pragma unroll
    for (int i = 0; i < 8; i++)
        acc8[i] += rbs0 * sWv3[0][8 * g + i] + rbs1 * sWv3[1][8 * g + i] + rbs2 * sWv3[2][8 * g + i];

    if (valid) {
        floatx4 st = { acc8[hf * 4 + 0], acc8[hf * 4 + 1], acc8[hf * 4 + 2], acc8[hf * 4 + 3] };
        ((floatx4*)out)[(size_t)n * 16 + g * 2 + hf] = st;
    }
}

// ---------------------------------------------------------------------------
extern "C" void kernel_launch(void* const* d_in, const int* in_sizes, int n_in,
                              void* d_out, int out_size, void* d_ws, size_t ws_size,
                              hipStream_t stream) {
    const float* coords0 = (const float*)d_in[0];
    const float* coords1 = (const float*)d_in[1];
    const float* feats0  = (const float*)d_in[2];
    const float* feats1  = (const float*)d_in[3];
    const int*   knn     = (const int*)d_in[4];
    const float* Wq      = (const float*)d_in[5];
    const float* bq      = (const float*)d_in[6];
    const float* Wk      = (const float*)d_in[7];
    const float* bk      = (const float*)d_in[8];
    const float* Wv      = (const float*)d_in[9];
    const float* bv      = (const float*)d_in[10];

    const int n0 = in_sizes[0] / 3;
    const int n1 = in_sizes[1] / 3;

    char* ws = (char*)d_ws;
    _Float16* KVh = (_Float16*)ws;                          // [n0][96] f16
    float*    Qf  = (float*)(ws + (size_t)n0 * 96 * 2);     // [n1][32] f32
    _Float16* fragKV = (_Float16*)(ws + (size_t)n0 * 96 * 2 + (size_t)n1 * 32 * 4);
    _Float16* fragQ  = fragKV + 6144;

    float* out    = (float*)d_out;                          // [n1,64]
    float* outIdx = out + (size_t)n1 * 64;                  // [1,n1,16] as float

    const int nb0 = (n0 + 63) / 64;
    const int nb1 = (n1 + 63) / 64;

    prep_weights<<<8, 256, 0, stream>>>(Wq, Wk, Wv, fragKV, fragQ);
    proj_fused<<<nb0 + nb1, 256, 0, stream>>>(feats0, feats1, fragKV, fragQ,
                                              bq, bk, bv, KVh, Qf, n0, n1, nb0);
    attn_kernel<<<(n1 + 15) / 16, 256, 0, stream>>>(coords0, coords1, knn,
                                                    Qf, KVh, Wk, Wv, out, outIdx, n1);
}